// Round 1
// baseline (8794.911 us; speedup 1.0000x reference)
//
#include <hip/hip_runtime.h>
#include <hip/hip_bf16.h>

#define D 768
#define BB 32
#define XX 256

// ---------------------------------------------------------------------------
// K1: GRU cell (fp32), fused gates-GEMM + combine. Also zeroes denom & argmax
// slot for this step, and gathers x = emb[token] when fed back.
// grid 384 blocks (2 d per block), 256 threads = 32 b x 2 d x 4 k-split.
// ---------------------------------------------------------------------------
__global__ __launch_bounds__(256) void k_gru(
    const float* __restrict__ xbase, long xbstride,
    const unsigned long long* __restrict__ toks,
    const float* __restrict__ hin,
    const float* __restrict__ wih, const float* __restrict__ whh,
    const float* __restrict__ bih, const float* __restrict__ bhh,
    float* __restrict__ hout,
    float* __restrict__ denom, unsigned long long* __restrict__ argz)
{
    __shared__ __align__(16) float xs[BB][130];
    __shared__ __align__(16) float hs[BB][130];
    __shared__ float part[256][6];
    __shared__ int tokl[BB];

    const int t = threadIdx.x;
    const int bid = blockIdx.x;
    if (bid == 0) {
        if (t < 32) denom[t] = 0.0f;
        else if (t < 64) argz[t - 32] = 0ULL;
    }
    const int b  = t & 31;
    const int g  = t >> 5;     // 0..7
    const int dd = g & 1;      // 0..1
    const int kh = g >> 1;     // 0..3
    const int dg = bid * 2 + dd;

    if (t < 32) tokl[t] = toks ? (int)(0xFFFFFFFFu - (unsigned)(toks[t] & 0xFFFFFFFFull)) : 0;

    const float* wr0 = wih + (long)dg * D;
    const float* wr1 = wih + (long)(768 + dg) * D;
    const float* wr2 = wih + (long)(1536 + dg) * D;
    const float* wh0 = whh + (long)dg * D;
    const float* wh1 = whh + (long)(768 + dg) * D;
    const float* wh2 = whh + (long)(1536 + dg) * D;

    float air = 0.f, aiz = 0.f, ain = 0.f, ahr = 0.f, ahz = 0.f, ahn = 0.f;

    for (int c = 0; c < 6; ++c) {
        const int kc = c * 128;
        __syncthreads();
        // stage x and h chunk (32 x 128 floats each) as float2
        for (int p = 0; p < 8; ++p) {
            int idx = t + 256 * p;           // 0..2047
            int bb  = idx >> 6;              // 0..31
            int k2  = (idx & 63) * 2;        // 0..126
            long xrow = toks ? (long)tokl[bb] * D : (long)bb * xbstride;
            float2 xv = *(const float2*)(xbase + xrow + kc + k2);
            *(float2*)&xs[bb][k2] = xv;
            float2 hv = *(const float2*)(hin + (long)bb * D + kc + k2);
            *(float2*)&hs[bb][k2] = hv;
        }
        __syncthreads();
        const int kbase = kh * 32;
        #pragma unroll
        for (int u = 0; u < 8; ++u) {
            const int kl = kbase + u * 4;
            const int kg = kc + kl;
            float4 wir = *(const float4*)(wr0 + kg);
            float4 wiz = *(const float4*)(wr1 + kg);
            float4 win = *(const float4*)(wr2 + kg);
            float4 whr = *(const float4*)(wh0 + kg);
            float4 whz = *(const float4*)(wh1 + kg);
            float4 whn = *(const float4*)(wh2 + kg);
            float2 x0 = *(const float2*)&xs[b][kl];
            float2 x1 = *(const float2*)&xs[b][kl + 2];
            float2 h0 = *(const float2*)&hs[b][kl];
            float2 h1 = *(const float2*)&hs[b][kl + 2];
            air += wir.x*x0.x + wir.y*x0.y + wir.z*x1.x + wir.w*x1.y;
            aiz += wiz.x*x0.x + wiz.y*x0.y + wiz.z*x1.x + wiz.w*x1.y;
            ain += win.x*x0.x + win.y*x0.y + win.z*x1.x + win.w*x1.y;
            ahr += whr.x*h0.x + whr.y*h0.y + whr.z*h1.x + whr.w*h1.y;
            ahz += whz.x*h0.x + whz.y*h0.y + whz.z*h1.x + whz.w*h1.y;
            ahn += whn.x*h0.x + whn.y*h0.y + whn.z*h1.x + whn.w*h1.y;
        }
    }
    part[t][0] = air; part[t][1] = aiz; part[t][2] = ain;
    part[t][3] = ahr; part[t][4] = ahz; part[t][5] = ahn;
    __syncthreads();
    if (t < 64) {
        float s[6];
        #pragma unroll
        for (int i = 0; i < 6; ++i)
            s[i] = part[t][i] + part[t + 64][i] + part[t + 128][i] + part[t + 192][i];
        const int b2  = t & 31;
        const int dg2 = bid * 2 + (t >> 5);
        float ir = s[0] + bih[dg2];
        float iz = s[1] + bih[768 + dg2];
        float in_ = s[2] + bih[1536 + dg2];
        float hr = s[3] + bhh[dg2];
        float hz = s[4] + bhh[768 + dg2];
        float hn = s[5] + bhh[1536 + dg2];
        float r = 1.0f / (1.0f + __expf(-(ir + hr)) * 0.0f + expf(-(ir + hr)) * 1.0f);
        // keep plain expf for precision:
        r = 1.0f / (1.0f + expf(-(ir + hr)));
        float z = 1.0f / (1.0f + expf(-(iz + hz)));
        float n = tanhf(in_ + r * hn);
        float hold = hin[(long)b2 * D + dg2];
        hout[(long)b2 * D + dg2] = (1.0f - z) * n + z * hold;
    }
}

// ---------------------------------------------------------------------------
// K2: fused vocab exp-logits (blocks [0,NV2)) + attention/p_gen (32 blocks).
// Vocab tile: 64 v x 32 b fp32, LDS staged; writes exp(logit) into out slice,
// accumulates softmax denominators via atomicAdd.
// ---------------------------------------------------------------------------
__global__ __launch_bounds__(256) void k_va(
    const float* __restrict__ hnew, const float* __restrict__ emb,
    const float* __restrict__ enc, const int* __restrict__ ids,
    const float* __restrict__ xbase, long xbstride,
    const unsigned long long* __restrict__ toks,
    const float* __restrict__ wgen, const float* __restrict__ bgen,
    float* __restrict__ out, int outoff, int JKV,
    float* __restrict__ denom, float* __restrict__ attnw,
    float* __restrict__ pgenp, int V, int NV2)
{
    __shared__ __align__(16) float smem[6336];
    const int t = threadIdx.x;
    const int bid = blockIdx.x;

    if (bid < NV2) {
        // -------------------- vocab block --------------------
        float (*es)[66] = (float(*)[66])smem;            // 64 x 66
        float (*hs)[66] = (float(*)[66])(smem + 64 * 66);// 32 x 66
        const int v0 = bid * 64;
        const int vq = t & 15;
        const int bq = t >> 4;   // 0..15
        float a0[4] = {0.f, 0.f, 0.f, 0.f};
        float a1[4] = {0.f, 0.f, 0.f, 0.f};
        for (int c = 0; c < 12; ++c) {
            const int kc = c * 64;
            __syncthreads();
            for (int p = 0; p < 8; ++p) {
                int idx = t + 256 * p;          // 0..2047
                int v   = idx >> 5;             // 0..63
                int k2  = (idx & 31) * 2;       // 0..62
                int vg  = v0 + v; if (vg >= V) vg = V - 1;
                float2 e = *(const float2*)(emb + (long)vg * D + kc + k2);
                *(float2*)&es[v][k2] = e;
            }
            for (int p = 0; p < 4; ++p) {
                int idx = t + 256 * p;          // 0..1023
                int bb  = idx >> 5;             // 0..31
                int k2  = (idx & 31) * 2;
                *(float2*)&hs[bb][k2] = *(const float2*)(hnew + (long)bb * D + kc + k2);
            }
            __syncthreads();
            #pragma unroll 8
            for (int k = 0; k < 64; k += 2) {
                float2 h0 = *(const float2*)&hs[bq][k];
                float2 h1 = *(const float2*)&hs[bq + 16][k];
                float2 e0 = *(const float2*)&es[vq][k];
                float2 e1 = *(const float2*)&es[vq + 16][k];
                float2 e2 = *(const float2*)&es[vq + 32][k];
                float2 e3 = *(const float2*)&es[vq + 48][k];
                a0[0] += h0.x*e0.x + h0.y*e0.y;
                a0[1] += h0.x*e1.x + h0.y*e1.y;
                a0[2] += h0.x*e2.x + h0.y*e2.y;
                a0[3] += h0.x*e3.x + h0.y*e3.y;
                a1[0] += h1.x*e0.x + h1.y*e0.y;
                a1[1] += h1.x*e1.x + h1.y*e1.y;
                a1[2] += h1.x*e2.x + h1.y*e2.y;
                a1[3] += h1.x*e3.x + h1.y*e3.y;
            }
        }
        float s0 = 0.f, s1 = 0.f;
        #pragma unroll
        for (int i = 0; i < 4; ++i) {
            int vg = v0 + vq + 16 * i;
            bool ok = vg < V;
            float e0v = ok ? expf(a0[i]) : 0.f;
            float e1v = ok ? expf(a1[i]) : 0.f;
            if (ok) {
                out[(long)bq * JKV + outoff + vg] = e0v;
                out[(long)(bq + 16) * JKV + outoff + vg] = e1v;
            }
            s0 += e0v; s1 += e1v;
        }
        for (int m = 1; m <= 8; m <<= 1) {
            s0 += __shfl_xor(s0, m);
            s1 += __shfl_xor(s1, m);
        }
        if (vq == 0) {
            atomicAdd(&denom[bq], s0);
            atomicAdd(&denom[bq + 16], s1);
        }
    } else {
        // -------------------- attention block (one per batch row) -----------
        const int b = bid - NV2;
        float* hh  = smem;          // 768
        float* xx  = smem + 768;    // 768
        float* cx  = smem + 1536;   // 768
        float* aw  = smem + 2304;   // 256
        float* red = smem + 2560;   // 256

        int tok = 0;
        if (toks) tok = (int)(0xFFFFFFFFu - (unsigned)(toks[b] & 0xFFFFFFFFull));
        const float* xr = toks ? (xbase + (long)tok * D) : (xbase + (long)b * xbstride);
        for (int i = 0; i < 3; ++i) {
            int k = t + 256 * i;
            hh[k] = hnew[(long)b * D + k];
            xx[k] = xr[k];
        }
        __syncthreads();
        // attn logit for x-position t
        const float* er = enc + ((long)b * XX + t) * D;
        float dot = 0.f;
        #pragma unroll 4
        for (int k4 = 0; k4 < D / 4; ++k4) {
            float4 e = *(const float4*)(er + k4 * 4);
            float4 h4 = *(const float4*)&hh[k4 * 4];
            dot += e.x*h4.x + e.y*h4.y + e.z*h4.z + e.w*h4.w;
        }
        int id = ids[b * XX + t];
        float l = (id == 0) ? -1e9f : dot;
        red[t] = l;
        __syncthreads();
        for (int s = 128; s > 0; s >>= 1) {
            if (t < s) red[t] = fmaxf(red[t], red[t + s]);
            __syncthreads();
        }
        float m = red[0];
        __syncthreads();
        float e = expf(l - m);
        red[t] = e;
        __syncthreads();
        for (int s = 128; s > 0; s >>= 1) {
            if (t < s) red[t] = red[t] + red[t + s];
            __syncthreads();
        }
        float sum = red[0];
        __syncthreads();
        float awv = e / sum;
        aw[t] = awv;
        attnw[b * XX + t] = awv;
        __syncthreads();
        // context
        for (int i = 0; i < 3; ++i) {
            int d = t + 256 * i;
            float c = 0.f;
            #pragma unroll 4
            for (int x = 0; x < XX; ++x)
                c += aw[x] * enc[((long)b * XX + x) * D + d];
            cx[d] = c;
        }
        __syncthreads();
        // p_gen = sigmoid(w_gen . [h, x, ctx] + b_gen)
        float s2 = 0.f;
        for (int i = 0; i < 9; ++i) {
            int idx = t + 256 * i;  // 0..2303
            float v = (idx < 768) ? hh[idx] : (idx < 1536) ? xx[idx - 768] : cx[idx - 1536];
            s2 += v * wgen[idx];
        }
        red[t] = s2;
        __syncthreads();
        for (int s = 128; s > 0; s >>= 1) {
            if (t < s) red[t] = red[t] + red[t + s];
            __syncthreads();
        }
        if (t == 0) pgenp[b] = 1.0f / (1.0f + expf(-(red[0] + bgen[0])));
    }
}

// ---------------------------------------------------------------------------
// K3: finalize: p_svg = pg*expv/denom + (1-pg)*p_ctx (scatter), write output,
// packed-64-bit argmax with first-index tie-break.
// grid: ceil(V/128) blocks, 256 threads.
// ---------------------------------------------------------------------------
__global__ __launch_bounds__(256) void k_fin(
    float* __restrict__ out, int outoff, int JKV,
    const float* __restrict__ denom, const float* __restrict__ attnw,
    const float* __restrict__ pgenp, const int* __restrict__ ids,
    unsigned long long* __restrict__ argz, int V)
{
    __shared__ float pctx[BB][128];
    __shared__ float pgl[BB], rdl[BB];
    const int t = threadIdx.x;
    const int v0 = blockIdx.x * 128;
    if (t < 32) { pgl[t] = pgenp[t]; rdl[t] = 1.0f / denom[t]; }
    for (int i = t; i < BB * 128; i += 256) ((float*)pctx)[i] = 0.f;
    __syncthreads();
    for (int i = 0; i < 32; ++i) {
        int idx = t + 256 * i;          // 0..8191
        int b = idx >> 8;
        int id = ids[idx];
        int rel = id - v0;
        if ((unsigned)rel < 128u) atomicAdd(&pctx[b][rel], attnw[idx]);
    }
    __syncthreads();
    for (int i = 0; i < 16; ++i) {
        int lin = t + 256 * i;
        int b = lin >> 7, v = lin & 127;
        int vg = v0 + v;
        unsigned long long pk = 0ULL;
        int b_save = b;
        if (vg < V) {
            long o = (long)b * JKV + outoff + vg;
            float e = out[o];
            float ps = pgl[b] * e * rdl[b] + (1.0f - pgl[b]) * pctx[b][v];
            out[o] = ps;
            pk = ((unsigned long long)__float_as_uint(ps) << 32)
               | (unsigned long long)(0xFFFFFFFFu - (unsigned)vg);
        }
        // b is constant across each 64-lane wave for fixed i
        for (int m = 1; m < 64; m <<= 1) {
            unsigned long long o2 = __shfl_xor(pk, m);
            pk = (o2 > pk) ? o2 : pk;
        }
        if ((t & 63) == 0) atomicMax(&argz[b_save], pk);
    }
}

// ---------------------------------------------------------------------------
extern "C" void kernel_launch(void* const* d_in, const int* in_sizes, int n_in,
                              void* d_out, int out_size, void* d_ws, size_t ws_size,
                              hipStream_t stream)
{
    const float* dec  = (const float*)d_in[0];
    const float* hid  = (const float*)d_in[1];
    const float* enc  = (const float*)d_in[2];
    const int*   ids  = (const int*)d_in[3];
    const float* emb  = (const float*)d_in[5];
    const float* wih  = (const float*)d_in[6];
    const float* whh  = (const float*)d_in[7];
    const float* bih  = (const float*)d_in[8];
    const float* bhh  = (const float*)d_in[9];
    const float* wgen = (const float*)d_in[10];
    const float* bgen = (const float*)d_in[11];
    float* out = (float*)d_out;

    const int B = 32;
    const int J = in_sizes[0] / (B * D);           // 4
    const int V = in_sizes[5] / D;                 // 30522
    const int K = out_size / (B * J * V);          // 8
    const int JKV = J * K * V;
    const int NV2 = (V + 63) / 64;                 // 477
    const int NV3 = (V + 127) / 128;               // 239

    // workspace carve
    char* w = (char*)d_ws;
    float* denom = (float*)w;  w += 256;
    float* pgenp = (float*)w;  w += 256;
    unsigned long long* argpack = (unsigned long long*)w; w += 1024; // 2 x 32
    float* attnw = (float*)w;  w += (size_t)B * XX * 4;
    float* h0 = (float*)w;     w += (size_t)B * D * 4;
    float* h1 = (float*)w;     /* end */

    int step = 0;
    for (int j = 0; j < J; ++j) {
        for (int kk = 0; kk < K; ++kk) {
            const int cur = step & 1;
            float* hout = (cur == 0) ? h0 : h1;
            const float* hin = (step == 0) ? hid : ((((step - 1) & 1) == 0) ? h0 : h1);
            const float* xbase;
            long xbs;
            const unsigned long long* toks;
            if (kk == 0) {
                xbase = dec + (long)j * D;
                xbs = (long)J * D;
                toks = nullptr;
            } else {
                xbase = emb;
                xbs = D;
                toks = argpack + ((step - 1) & 1) * 32;
            }
            unsigned long long* argz = argpack + cur * 32;
            const int outoff = (j * K + kk) * V;

            k_gru<<<dim3(384), dim3(256), 0, stream>>>(
                xbase, xbs, toks, hin, wih, whh, bih, bhh, hout, denom, argz);
            k_va<<<dim3(NV2 + 32), dim3(256), 0, stream>>>(
                hout, emb, enc, ids, xbase, xbs, toks, wgen, bgen,
                out, outoff, JKV, denom, attnw, pgenp, V, NV2);
            k_fin<<<dim3(NV3), dim3(256), 0, stream>>>(
                out, outoff, JKV, denom, attnw, pgenp, ids, argz, V);
            ++step;
        }
    }
}

// Round 2
// 8262.931 us; speedup vs baseline: 1.0644x; 1.0644x over previous
//
#include <hip/hip_runtime.h>
#include <hip/hip_bf16.h>

#define D 768
#define BB 32
#define XX 256

typedef __bf16 bf16x8 __attribute__((ext_vector_type(8)));
typedef float  f32x4  __attribute__((ext_vector_type(4)));

// ---------------------------------------------------------------------------
// K0: one-time per call: emb fp32 -> bf16
// ---------------------------------------------------------------------------
__global__ __launch_bounds__(256) void k_cvt(const float* __restrict__ src,
                                             __bf16* __restrict__ dst, int n8)
{
    int i = blockIdx.x * 256 + threadIdx.x;
    if (i < n8) {
        float4 f0 = *(const float4*)(src + (size_t)i * 8);
        float4 f1 = *(const float4*)(src + (size_t)i * 8 + 4);
        bf16x8 o;
        o[0] = (__bf16)f0.x; o[1] = (__bf16)f0.y; o[2] = (__bf16)f0.z; o[3] = (__bf16)f0.w;
        o[4] = (__bf16)f1.x; o[5] = (__bf16)f1.y; o[6] = (__bf16)f1.z; o[7] = (__bf16)f1.w;
        *(bf16x8*)(dst + (size_t)i * 8) = o;
    }
}

// ---------------------------------------------------------------------------
// K1: GRU gates GEMM, fp32. One dot (K=768) per thread; weights read ONCE
// per step (broadcast within 32-lane groups). gT layout: [row 0..4607][b 0..31]
// rows 0..2303 = gi (x @ w_ih^T), 2304..4607 = gh (h @ w_hh^T).
// grid 576 blocks x 256 threads (8 rows x 32 b per block).
// ---------------------------------------------------------------------------
__global__ __launch_bounds__(256) void k_gates(
    const float* __restrict__ xbase, long xbstride,
    const unsigned long long* __restrict__ toks,
    const float* __restrict__ hin,
    const float* __restrict__ wih, const float* __restrict__ whh,
    float* __restrict__ gT)
{
    __shared__ __align__(16) float vec[BB][132];
    __shared__ int tokl[BB];
    const int t = threadIdx.x, bid = blockIdx.x;
    const int b = t & 31, rl = t >> 5;
    const int rglob = bid * 8 + rl;            // 0..4607
    const bool isH = rglob >= 2304;            // block-uniform (2304 % 8 == 0)
    const int row = isH ? rglob - 2304 : rglob;
    const float* w = (isH ? whh : wih) + (size_t)row * D;
    if (t < 32) tokl[t] = toks ? (int)(0xFFFFFFFFu - (unsigned)(toks[t] & 0xFFFFFFFFull)) : 0;

    float acc = 0.f;
    for (int c = 0; c < 6; ++c) {
        const int kc = c * 128;
        __syncthreads();
        for (int p = 0; p < 4; ++p) {
            int fid = t + 256 * p;             // 0..1023
            int bb = fid >> 5, k4 = (fid & 31) * 4;
            const float* src;
            if (isH) src = hin + (size_t)bb * D;
            else     src = toks ? (xbase + (size_t)tokl[bb] * D)
                                : (xbase + (size_t)bb * xbstride);
            *(float4*)&vec[bb][k4] = *(const float4*)(src + kc + k4);
        }
        __syncthreads();
        #pragma unroll
        for (int k4 = 0; k4 < 128; k4 += 4) {
            float4 wv = *(const float4*)(w + kc + k4);
            float4 xv = *(const float4*)&vec[b][k4];
            acc += wv.x * xv.x + wv.y * xv.y + wv.z * xv.z + wv.w * xv.w;
        }
    }
    gT[(size_t)rglob * 32 + b] = acc;
}

// ---------------------------------------------------------------------------
// K2: GRU combine: gates -> h (fp32 + bf16). Also zeroes denomP / argz.
// grid 96 blocks x 256 threads (8 d x 32 b).
// ---------------------------------------------------------------------------
__global__ __launch_bounds__(256) void k_comb(
    const float* __restrict__ gT,
    const float* __restrict__ bih, const float* __restrict__ bhh,
    const float* __restrict__ hin,
    float* __restrict__ hout, __bf16* __restrict__ hbf,
    float* __restrict__ denomP, unsigned long long* __restrict__ argz)
{
    const int t = threadIdx.x, bid = blockIdx.x;
    const int b = t & 31, dl = t >> 5;
    const int d = bid * 8 + dl;
    if (bid == 0) {
        denomP[t] = 0.f;
        if (t < 32) argz[t] = 0ULL;
    }
    float ir = gT[(size_t)d * 32 + b]            + bih[d];
    float iz = gT[(size_t)(768 + d) * 32 + b]    + bih[768 + d];
    float in_ = gT[(size_t)(1536 + d) * 32 + b]  + bih[1536 + d];
    float hr = gT[(size_t)(2304 + d) * 32 + b]   + bhh[d];
    float hz = gT[(size_t)(3072 + d) * 32 + b]   + bhh[768 + d];
    float hn = gT[(size_t)(3840 + d) * 32 + b]   + bhh[1536 + d];
    float r = 1.0f / (1.0f + expf(-(ir + hr)));
    float z = 1.0f / (1.0f + expf(-(iz + hz)));
    float n = tanhf(in_ + r * hn);
    float hold = hin[(size_t)b * D + d];
    float hv = (1.0f - z) * n + z * hold;
    hout[(size_t)b * D + d] = hv;
    hbf[(size_t)b * D + d] = (__bf16)hv;
}

// ---------------------------------------------------------------------------
// K3: fused vocab exp-logits via bf16 MFMA (blocks [0,NVB)) + attention/p_gen
// (32 blocks). Vocab: each wave = 16 vocab x 32 batch, K=768, no LDS in the
// K-loop. Writes exp(logit) to out slice; denominators -> LDS -> denomP slice.
// ---------------------------------------------------------------------------
__global__ __launch_bounds__(256) void k_voca(
    const float* __restrict__ hnew, const __bf16* __restrict__ hbf,
    const __bf16* __restrict__ embbf,
    const float* __restrict__ enc, const int* __restrict__ ids,
    const float* __restrict__ xbase, long xbstride,
    const unsigned long long* __restrict__ toks,
    const float* __restrict__ wgen, const float* __restrict__ bgen,
    float* __restrict__ out, long outoff, long JKV,
    float* __restrict__ denomP, float* __restrict__ attnw,
    float* __restrict__ pgenp, int V, int NVB)
{
    __shared__ __align__(16) float smem[2816];
    const int t = threadIdx.x;
    const int bid = blockIdx.x;

    if (bid < NVB) {
        // -------------------- vocab MFMA block --------------------
        float* dsum = smem;                  // 32 floats
        if (t < 32) dsum[t] = 0.f;
        __syncthreads();

        const int lane = t & 63, w = t >> 6;
        const int col = lane & 15;           // n (vocab within tile) / m (batch) index
        const int kq  = (lane >> 4) * 8;     // k offset within 32-chunk
        int vrow = bid * 64 + w * 16 + col;
        const bool ok = vrow < V;
        const int vl = ok ? vrow : V - 1;
        const __bf16* bp  = embbf + (size_t)vl * D + kq;
        const __bf16* ap0 = hbf + (size_t)col * D + kq;
        const __bf16* ap1 = hbf + (size_t)(col + 16) * D + kq;

        f32x4 c0 = {0.f, 0.f, 0.f, 0.f};
        f32x4 c1 = {0.f, 0.f, 0.f, 0.f};
        #pragma unroll 4
        for (int kc = 0; kc < D; kc += 32) {
            bf16x8 bv = *(const bf16x8*)(bp + kc);
            bf16x8 a0 = *(const bf16x8*)(ap0 + kc);
            bf16x8 a1 = *(const bf16x8*)(ap1 + kc);
            c0 = __builtin_amdgcn_mfma_f32_16x16x32_bf16(a0, bv, c0, 0, 0, 0);
            c1 = __builtin_amdgcn_mfma_f32_16x16x32_bf16(a1, bv, c1, 0, 0, 0);
        }
        #pragma unroll
        for (int r = 0; r < 4; ++r) {
            int b0 = (lane >> 4) * 4 + r;    // batch row for c0
            float e0 = ok ? __expf(c0[r]) : 0.f;
            float e1 = ok ? __expf(c1[r]) : 0.f;
            if (ok) {
                out[(size_t)b0 * JKV + outoff + vrow] = e0;
                out[(size_t)(b0 + 16) * JKV + outoff + vrow] = e1;
            }
            #pragma unroll
            for (int m = 1; m <= 8; m <<= 1) {
                e0 += __shfl_xor(e0, m);
                e1 += __shfl_xor(e1, m);
            }
            if (col == 0) {
                atomicAdd(&dsum[b0], e0);
                atomicAdd(&dsum[b0 + 16], e1);
            }
        }
        __syncthreads();
        if (t < 32) atomicAdd(&denomP[(bid & 7) * 32 + t], dsum[t]);
    } else {
        // -------------------- attention block (one per batch row) -----------
        const int b = bid - NVB;
        float* hh  = smem;          // 768
        float* xx  = smem + 768;    // 768
        float* cx  = smem + 1536;   // 768
        float* aw  = smem + 2304;   // 256
        float* red = smem + 2560;   // 256

        int tok = 0;
        if (toks) tok = (int)(0xFFFFFFFFu - (unsigned)(toks[b] & 0xFFFFFFFFull));
        const float* xr = toks ? (xbase + (size_t)tok * D) : (xbase + (size_t)b * xbstride);
        for (int i = 0; i < 3; ++i) {
            int k = t + 256 * i;
            hh[k] = hnew[(size_t)b * D + k];
            xx[k] = xr[k];
        }
        __syncthreads();
        const float* er = enc + ((size_t)b * XX + t) * D;
        float dot = 0.f;
        #pragma unroll 4
        for (int k4 = 0; k4 < D / 4; ++k4) {
            float4 e = *(const float4*)(er + k4 * 4);
            float4 h4 = *(const float4*)&hh[k4 * 4];
            dot += e.x * h4.x + e.y * h4.y + e.z * h4.z + e.w * h4.w;
        }
        int id = ids[b * XX + t];
        float l = (id == 0) ? -1e9f : dot;
        red[t] = l;
        __syncthreads();
        for (int s = 128; s > 0; s >>= 1) {
            if (t < s) red[t] = fmaxf(red[t], red[t + s]);
            __syncthreads();
        }
        float m = red[0];
        __syncthreads();
        float e = expf(l - m);
        red[t] = e;
        __syncthreads();
        for (int s = 128; s > 0; s >>= 1) {
            if (t < s) red[t] = red[t] + red[t + s];
            __syncthreads();
        }
        float sum = red[0];
        __syncthreads();
        float awv = e / sum;
        aw[t] = awv;
        attnw[b * XX + t] = awv;
        __syncthreads();
        for (int i = 0; i < 3; ++i) {
            int d = t + 256 * i;
            float c = 0.f;
            #pragma unroll 4
            for (int x = 0; x < XX; ++x)
                c += aw[x] * enc[((size_t)b * XX + x) * D + d];
            cx[d] = c;
        }
        __syncthreads();
        float s2 = 0.f;
        for (int i = 0; i < 9; ++i) {
            int idx = t + 256 * i;  // 0..2303
            float v = (idx < 768) ? hh[idx] : (idx < 1536) ? xx[idx - 768] : cx[idx - 1536];
            s2 += v * wgen[idx];
        }
        red[t] = s2;
        __syncthreads();
        for (int s = 128; s > 0; s >>= 1) {
            if (t < s) red[t] = red[t] + red[t + s];
            __syncthreads();
        }
        if (t == 0) pgenp[b] = 1.0f / (1.0f + expf(-(red[0] + bgen[0])));
    }
}

// ---------------------------------------------------------------------------
// K4: finalize: p_svg = pg*expv/denom + (1-pg)*p_ctx (scatter), write output,
// packed-64-bit argmax with first-index tie-break. grid ceil(V/128) x 256.
// ---------------------------------------------------------------------------
__global__ __launch_bounds__(256) void k_fin(
    float* __restrict__ out, long outoff, long JKV,
    const float* __restrict__ denomP, const float* __restrict__ attnw,
    const float* __restrict__ pgenp, const int* __restrict__ ids,
    unsigned long long* __restrict__ argz, int V)
{
    __shared__ float pctx[BB][128];
    __shared__ float pgl[BB], rdl[BB];
    const int t = threadIdx.x;
    const int v0 = blockIdx.x * 128;
    if (t < 32) {
        pgl[t] = pgenp[t];
        float s = 0.f;
        #pragma unroll
        for (int i = 0; i < 8; ++i) s += denomP[i * 32 + t];
        rdl[t] = 1.0f / s;
    }
    for (int i = t; i < BB * 128; i += 256) ((float*)pctx)[i] = 0.f;
    __syncthreads();
    for (int i = 0; i < 32; ++i) {
        int idx = t + 256 * i;          // 0..8191
        int b = idx >> 8;
        int id = ids[idx];
        int rel = id - v0;
        if ((unsigned)rel < 128u) atomicAdd(&pctx[b][rel], attnw[idx]);
    }
    __syncthreads();
    for (int i = 0; i < 16; ++i) {
        int lin = t + 256 * i;
        int b = lin >> 7, v = lin & 127;
        int vg = v0 + v;
        unsigned long long pk = 0ULL;
        int b_save = b;
        if (vg < V) {
            size_t o = (size_t)b * JKV + outoff + vg;
            float e = out[o];
            float ps = pgl[b] * e * rdl[b] + (1.0f - pgl[b]) * pctx[b][v];
            out[o] = ps;
            pk = ((unsigned long long)__float_as_uint(ps) << 32)
               | (unsigned long long)(0xFFFFFFFFu - (unsigned)vg);
        }
        for (int m = 1; m < 64; m <<= 1) {
            unsigned long long o2 = __shfl_xor(pk, m);
            pk = (o2 > pk) ? o2 : pk;
        }
        if ((t & 63) == 0) atomicMax(&argz[b_save], pk);
    }
}

// ---------------------------------------------------------------------------
extern "C" void kernel_launch(void* const* d_in, const int* in_sizes, int n_in,
                              void* d_out, int out_size, void* d_ws, size_t ws_size,
                              hipStream_t stream)
{
    const float* dec  = (const float*)d_in[0];
    const float* hid  = (const float*)d_in[1];
    const float* enc  = (const float*)d_in[2];
    const int*   ids  = (const int*)d_in[3];
    const float* emb  = (const float*)d_in[5];
    const float* wih  = (const float*)d_in[6];
    const float* whh  = (const float*)d_in[7];
    const float* bih  = (const float*)d_in[8];
    const float* bhh  = (const float*)d_in[9];
    const float* wgen = (const float*)d_in[10];
    const float* bgen = (const float*)d_in[11];
    float* out = (float*)d_out;

    const int B = 32;
    const int J = in_sizes[0] / (B * D);           // 4
    const int V = in_sizes[5] / D;                 // 30522
    const int K = out_size / (B * J * V);          // 8
    const long JKV = (long)J * K * V;
    const int NVB = (V + 63) / 64;                 // 477
    const int NV3 = (V + 127) / 128;               // 239

    // workspace carve
    char* w = (char*)d_ws;
    float* denomP = (float*)w;  w += 1024;                       // 8 x 32
    float* pgenp  = (float*)w;  w += 256;
    unsigned long long* argpack = (unsigned long long*)w; w += 1024; // 2 x 32
    float* attnw  = (float*)w;  w += (size_t)B * XX * 4;
    float* gT     = (float*)w;  w += (size_t)4608 * 32 * 4;
    float* h0     = (float*)w;  w += (size_t)B * D * 4;
    float* h1     = (float*)w;  w += (size_t)B * D * 4;
    __bf16* hbf   = (__bf16*)w; w += (size_t)B * D * 2;
    __bf16* embbf = (__bf16*)w; w += (size_t)V * D * 2;

    // one-time emb conversion (per call)
    const int n8 = V * D / 8;
    k_cvt<<<dim3((n8 + 255) / 256), dim3(256), 0, stream>>>(emb, embbf, n8);

    int step = 0;
    for (int j = 0; j < J; ++j) {
        for (int kk = 0; kk < K; ++kk) {
            const int cur = step & 1;
            float* hout = (cur == 0) ? h0 : h1;
            const float* hin = (step == 0) ? hid : ((((step - 1) & 1) == 0) ? h0 : h1);
            const float* xbase;
            long xbs;
            const unsigned long long* toks;
            if (kk == 0) {
                xbase = dec + (size_t)j * D;
                xbs = (long)J * D;
                toks = nullptr;
            } else {
                xbase = emb;
                xbs = D;
                toks = argpack + ((step - 1) & 1) * 32;
            }
            unsigned long long* argz = argpack + cur * 32;
            const long outoff = (long)(j * K + kk) * V;

            k_gates<<<dim3(576), dim3(256), 0, stream>>>(
                xbase, xbs, toks, hin, wih, whh, gT);
            k_comb<<<dim3(96), dim3(256), 0, stream>>>(
                gT, bih, bhh, hin, hout, hbf, denomP, argz);
            k_voca<<<dim3(NVB + 32), dim3(256), 0, stream>>>(
                hout, hbf, embbf, enc, ids, xbase, xbs, toks, wgen, bgen,
                out, outoff, JKV, denomP, attnw, pgenp, V, NVB);
            k_fin<<<dim3(NV3), dim3(256), 0, stream>>>(
                out, outoff, JKV, denomP, attnw, pgenp, ids, argz, V);
            ++step;
        }
    }
}

// Round 3
// 3918.542 us; speedup vs baseline: 2.2444x; 2.1087x over previous
//
#include <hip/hip_runtime.h>
#include <hip/hip_bf16.h>

#define D 768
#define BB 32
#define XX 256
#define CH 3816   // vocab chunk per k_fin block (8 chunks cover 30522)

typedef __bf16 bf16x8 __attribute__((ext_vector_type(8)));
typedef float  f32x4  __attribute__((ext_vector_type(4)));

// ---------------------------------------------------------------------------
// K0: one-time per call: emb fp32 -> bf16
// ---------------------------------------------------------------------------
__global__ __launch_bounds__(256) void k_cvt(const float* __restrict__ src,
                                             __bf16* __restrict__ dst, int n8)
{
    int i = blockIdx.x * 256 + threadIdx.x;
    if (i < n8) {
        float4 f0 = *(const float4*)(src + (size_t)i * 8);
        float4 f1 = *(const float4*)(src + (size_t)i * 8 + 4);
        bf16x8 o;
        o[0] = (__bf16)f0.x; o[1] = (__bf16)f0.y; o[2] = (__bf16)f0.z; o[3] = (__bf16)f0.w;
        o[4] = (__bf16)f1.x; o[5] = (__bf16)f1.y; o[6] = (__bf16)f1.z; o[7] = (__bf16)f1.w;
        *(bf16x8*)(dst + (size_t)i * 8) = o;
    }
}

// ---------------------------------------------------------------------------
// K1: GRU gates GEMM, fp32. One dot (K=768) per thread; weights read once per
// step. gT layout: [row 0..4607][b 0..31]; rows 0..2303 = gi, 2304..4607 = gh.
// grid 576 x 256 (8 rows x 32 b per block).
// ---------------------------------------------------------------------------
__global__ __launch_bounds__(256) void k_gates(
    const float* __restrict__ xbase, long xbstride,
    const unsigned long long* __restrict__ toks,
    const float* __restrict__ hin,
    const float* __restrict__ wih, const float* __restrict__ whh,
    float* __restrict__ gT)
{
    __shared__ __align__(16) float vec[BB][132];
    __shared__ int tokl[BB];
    const int t = threadIdx.x, bid = blockIdx.x;
    const int b = t & 31, rl = t >> 5;
    const int rglob = bid * 8 + rl;            // 0..4607
    const bool isH = rglob >= 2304;            // block-uniform (2304 % 8 == 0)
    const int row = isH ? rglob - 2304 : rglob;
    const float* w = (isH ? whh : wih) + (size_t)row * D;
    if (t < 32) tokl[t] = toks ? (int)(0xFFFFFFFFu - (unsigned)(toks[t] & 0xFFFFFFFFull)) : 0;

    float acc = 0.f;
    for (int c = 0; c < 6; ++c) {
        const int kc = c * 128;
        __syncthreads();
        for (int p = 0; p < 4; ++p) {
            int fid = t + 256 * p;             // 0..1023
            int bb = fid >> 5, k4 = (fid & 31) * 4;
            const float* src;
            if (isH) src = hin + (size_t)bb * D;
            else     src = toks ? (xbase + (size_t)tokl[bb] * D)
                                : (xbase + (size_t)bb * xbstride);
            *(float4*)&vec[bb][k4] = *(const float4*)(src + kc + k4);
        }
        __syncthreads();
        #pragma unroll
        for (int k4 = 0; k4 < 128; k4 += 4) {
            float4 wv = *(const float4*)(w + kc + k4);
            float4 xv = *(const float4*)&vec[b][k4];
            acc += wv.x * xv.x + wv.y * xv.y + wv.z * xv.z + wv.w * xv.w;
        }
    }
    gT[(size_t)rglob * 32 + b] = acc;
}

// ---------------------------------------------------------------------------
// K2: GRU combine: gates -> h (fp32 + bf16). Zeroes argz for this step.
// grid 96 x 256 (8 d x 32 b).
// ---------------------------------------------------------------------------
__global__ __launch_bounds__(256) void k_comb(
    const float* __restrict__ gT,
    const float* __restrict__ bih, const float* __restrict__ bhh,
    const float* __restrict__ hin,
    float* __restrict__ hout, __bf16* __restrict__ hbf,
    unsigned long long* __restrict__ argz)
{
    const int t = threadIdx.x, bid = blockIdx.x;
    const int b = t & 31, dl = t >> 5;
    const int d = bid * 8 + dl;
    if (bid == 0 && t < 32) argz[t] = 0ULL;
    float ir = gT[(size_t)d * 32 + b]            + bih[d];
    float iz = gT[(size_t)(768 + d) * 32 + b]    + bih[768 + d];
    float in_ = gT[(size_t)(1536 + d) * 32 + b]  + bih[1536 + d];
    float hr = gT[(size_t)(2304 + d) * 32 + b]   + bhh[d];
    float hz = gT[(size_t)(3072 + d) * 32 + b]   + bhh[768 + d];
    float hn = gT[(size_t)(3840 + d) * 32 + b]   + bhh[1536 + d];
    float r = 1.0f / (1.0f + expf(-(ir + hr)));
    float z = 1.0f / (1.0f + expf(-(iz + hz)));
    float n = tanhf(in_ + r * hn);
    float hold = hin[(size_t)b * D + d];
    float hv = (1.0f - z) * n + z * hold;
    hout[(size_t)b * D + d] = hv;
    hbf[(size_t)b * D + d] = (__bf16)hv;
}

// ---------------------------------------------------------------------------
// K3: fused vocab exp-logits via bf16 MFMA (blocks [0,NVB)) + attention/p_gen
// (32 blocks). Vocab: wave = 16 vocab x 32 batch, K=768, no LDS in K-loop.
// Writes exp(logit) to out slice; per-block denominator partials -> plain
// stores dpartT[b][bid] (NO global atomics).
// ---------------------------------------------------------------------------
__global__ __launch_bounds__(256) void k_voca(
    const float* __restrict__ hnew, const __bf16* __restrict__ hbf,
    const __bf16* __restrict__ embbf,
    const float* __restrict__ enc, const int* __restrict__ ids,
    const float* __restrict__ xbase, long xbstride,
    const unsigned long long* __restrict__ toks,
    const float* __restrict__ wgen, const float* __restrict__ bgen,
    float* __restrict__ out, long outoff, long JKV,
    float* __restrict__ dpartT, float* __restrict__ attnw,
    float* __restrict__ pgenp, int V, int NVB)
{
    __shared__ __align__(16) float smem[2816];
    const int t = threadIdx.x;
    const int bid = blockIdx.x;

    if (bid < NVB) {
        // -------------------- vocab MFMA block --------------------
        float* dsum = smem;                  // 32 floats
        if (t < 32) dsum[t] = 0.f;
        __syncthreads();

        const int lane = t & 63, w = t >> 6;
        const int col = lane & 15;
        const int kq  = (lane >> 4) * 8;
        int vrow = bid * 64 + w * 16 + col;
        const bool ok = vrow < V;
        const int vl = ok ? vrow : V - 1;
        const __bf16* bp  = embbf + (size_t)vl * D + kq;
        const __bf16* ap0 = hbf + (size_t)col * D + kq;
        const __bf16* ap1 = hbf + (size_t)(col + 16) * D + kq;

        f32x4 c0 = {0.f, 0.f, 0.f, 0.f};
        f32x4 c1 = {0.f, 0.f, 0.f, 0.f};
        #pragma unroll 4
        for (int kc = 0; kc < D; kc += 32) {
            bf16x8 bv = *(const bf16x8*)(bp + kc);
            bf16x8 a0 = *(const bf16x8*)(ap0 + kc);
            bf16x8 a1 = *(const bf16x8*)(ap1 + kc);
            c0 = __builtin_amdgcn_mfma_f32_16x16x32_bf16(a0, bv, c0, 0, 0, 0);
            c1 = __builtin_amdgcn_mfma_f32_16x16x32_bf16(a1, bv, c1, 0, 0, 0);
        }
        #pragma unroll
        for (int r = 0; r < 4; ++r) {
            int b0 = (lane >> 4) * 4 + r;    // batch row for c0
            float e0 = ok ? __expf(c0[r]) : 0.f;
            float e1 = ok ? __expf(c1[r]) : 0.f;
            if (ok) {
                out[(size_t)b0 * JKV + outoff + vrow] = e0;
                out[(size_t)(b0 + 16) * JKV + outoff + vrow] = e1;
            }
            #pragma unroll
            for (int m = 1; m <= 8; m <<= 1) {
                e0 += __shfl_xor(e0, m);
                e1 += __shfl_xor(e1, m);
            }
            if (col == 0) {
                atomicAdd(&dsum[b0], e0);        // LDS atomic — cheap
                atomicAdd(&dsum[b0 + 16], e1);
            }
        }
        __syncthreads();
        if (t < 32) dpartT[(size_t)t * 512 + bid] = dsum[t];   // plain store
    } else {
        // -------------------- attention block (one per batch row) -----------
        const int b = bid - NVB;
        float* hh  = smem;          // 768
        float* xx  = smem + 768;    // 768
        float* cx  = smem + 1536;   // 768
        float* aw  = smem + 2304;   // 256
        float* red = smem + 2560;   // 256

        int tok = 0;
        if (toks) tok = (int)(0xFFFFFFFFu - (unsigned)(toks[b] & 0xFFFFFFFFull));
        const float* xr = toks ? (xbase + (size_t)tok * D) : (xbase + (size_t)b * xbstride);
        for (int i = 0; i < 3; ++i) {
            int k = t + 256 * i;
            hh[k] = hnew[(size_t)b * D + k];
            xx[k] = xr[k];
        }
        __syncthreads();
        const float* er = enc + ((size_t)b * XX + t) * D;
        float dot = 0.f;
        #pragma unroll 4
        for (int k4 = 0; k4 < D / 4; ++k4) {
            float4 e = *(const float4*)(er + k4 * 4);
            float4 h4 = *(const float4*)&hh[k4 * 4];
            dot += e.x * h4.x + e.y * h4.y + e.z * h4.z + e.w * h4.w;
        }
        int id = ids[b * XX + t];
        float l = (id == 0) ? -1e9f : dot;
        red[t] = l;
        __syncthreads();
        for (int s = 128; s > 0; s >>= 1) {
            if (t < s) red[t] = fmaxf(red[t], red[t + s]);
            __syncthreads();
        }
        float m = red[0];
        __syncthreads();
        float e = expf(l - m);
        red[t] = e;
        __syncthreads();
        for (int s = 128; s > 0; s >>= 1) {
            if (t < s) red[t] = red[t] + red[t + s];
            __syncthreads();
        }
        float sum = red[0];
        __syncthreads();
        float awv = e / sum;
        aw[t] = awv;
        attnw[b * XX + t] = awv;
        __syncthreads();
        for (int i = 0; i < 3; ++i) {
            int d = t + 256 * i;
            float c = 0.f;
            #pragma unroll 4
            for (int x = 0; x < XX; ++x)
                c += aw[x] * enc[((size_t)b * XX + x) * D + d];
            cx[d] = c;
        }
        __syncthreads();
        float s2 = 0.f;
        for (int i = 0; i < 9; ++i) {
            int idx = t + 256 * i;  // 0..2303
            float v = (idx < 768) ? hh[idx] : (idx < 1536) ? xx[idx - 768] : cx[idx - 1536];
            s2 += v * wgen[idx];
        }
        red[t] = s2;
        __syncthreads();
        for (int s = 128; s > 0; s >>= 1) {
            if (t < s) red[t] = red[t] + red[t + s];
            __syncthreads();
        }
        if (t == 0) pgenp[b] = 1.0f / (1.0f + expf(-(red[0] + bgen[0])));
    }
}

// ---------------------------------------------------------------------------
// K4: finalize. Grid = 32 b x 8 vocab chunks (256 blocks, one per CU).
// Each block: reduce denom[b] from partials (coalesced), scatter its b's 256
// attention weights into a CH-entry LDS chunk, normalize out slice, register
// argmax -> ONE atomicMax per block.
// ---------------------------------------------------------------------------
__global__ __launch_bounds__(256) void k_fin(
    float* __restrict__ out, long outoff, long JKV,
    const float* __restrict__ dpartT, int npart,
    const float* __restrict__ attnw,
    const float* __restrict__ pgenp, const int* __restrict__ ids,
    unsigned long long* __restrict__ argz, int V)
{
    __shared__ float pctx[CH];
    __shared__ float red[256];
    __shared__ unsigned long long wmax[4];
    const int t = threadIdx.x;
    const int b = blockIdx.x >> 3;      // 0..31
    const int c = blockIdx.x & 7;       // 0..7
    const int v0 = c * CH;

    // denominator for this b (coalesced partial reads)
    float s = 0.f;
    for (int i = t; i < npart; i += 256) s += dpartT[(size_t)b * 512 + i];
    red[t] = s;
    __syncthreads();
    for (int st = 128; st > 0; st >>= 1) {
        if (t < st) red[t] += red[t + st];
        __syncthreads();
    }
    const float rd = 1.0f / red[0];
    const float pg = pgenp[b];
    const float og = 1.0f - pg;

    for (int i = t; i < CH; i += 256) pctx[i] = 0.f;
    __syncthreads();
    {
        int id = ids[b * XX + t];
        int rel = id - v0;
        if ((unsigned)rel < (unsigned)CH) atomicAdd(&pctx[rel], attnw[b * XX + t]);
    }
    __syncthreads();

    unsigned long long pk = 0ULL;
    const int vend = (v0 + CH < V) ? CH : (V - v0);
    #pragma unroll
    for (int i = 0; i < 15; ++i) {
        int v = t + 256 * i;
        if (v < vend) {
            int vg = v0 + v;
            size_t o = (size_t)b * JKV + outoff + vg;
            float e = out[o];
            float ps = pg * e * rd + og * pctx[v];
            out[o] = ps;
            unsigned long long k2 = ((unsigned long long)__float_as_uint(ps) << 32)
                                  | (unsigned long long)(0xFFFFFFFFu - (unsigned)vg);
            if (k2 > pk) pk = k2;
        }
    }
    #pragma unroll
    for (int m = 1; m < 64; m <<= 1) {
        unsigned long long o2 = __shfl_xor(pk, m);
        if (o2 > pk) pk = o2;
    }
    if ((t & 63) == 0) wmax[t >> 6] = pk;
    __syncthreads();
    if (t == 0) {
        unsigned long long m0 = wmax[0];
        #pragma unroll
        for (int i2 = 1; i2 < 4; ++i2) if (wmax[i2] > m0) m0 = wmax[i2];
        atomicMax(&argz[b], m0);
    }
}

// ---------------------------------------------------------------------------
extern "C" void kernel_launch(void* const* d_in, const int* in_sizes, int n_in,
                              void* d_out, int out_size, void* d_ws, size_t ws_size,
                              hipStream_t stream)
{
    const float* dec  = (const float*)d_in[0];
    const float* hid  = (const float*)d_in[1];
    const float* enc  = (const float*)d_in[2];
    const int*   ids  = (const int*)d_in[3];
    const float* emb  = (const float*)d_in[5];
    const float* wih  = (const float*)d_in[6];
    const float* whh  = (const float*)d_in[7];
    const float* bih  = (const float*)d_in[8];
    const float* bhh  = (const float*)d_in[9];
    const float* wgen = (const float*)d_in[10];
    const float* bgen = (const float*)d_in[11];
    float* out = (float*)d_out;

    const int B = 32;
    const int J = in_sizes[0] / (B * D);           // 4
    const int V = in_sizes[5] / D;                 // 30522
    const int K = out_size / (B * J * V);          // 8
    const long JKV = (long)J * K * V;
    const int NVB = (V + 63) / 64;                 // 477

    // workspace carve
    char* w = (char*)d_ws;
    float* pgenp  = (float*)w;  w += 256;
    unsigned long long* argpack = (unsigned long long*)w; w += 1024; // 2 x 32
    float* attnw  = (float*)w;  w += (size_t)B * XX * 4;
    float* gT     = (float*)w;  w += (size_t)4608 * 32 * 4;
    float* dpartT = (float*)w;  w += (size_t)32 * 512 * 4;
    float* h0     = (float*)w;  w += (size_t)B * D * 4;
    float* h1     = (float*)w;  w += (size_t)B * D * 4;
    __bf16* hbf   = (__bf16*)w; w += (size_t)B * D * 2;
    __bf16* embbf = (__bf16*)w; w += (size_t)V * D * 2;

    const int n8 = V * D / 8;
    k_cvt<<<dim3((n8 + 255) / 256), dim3(256), 0, stream>>>(emb, embbf, n8);

    int step = 0;
    for (int j = 0; j < J; ++j) {
        for (int kk = 0; kk < K; ++kk) {
            const int cur = step & 1;
            float* hout = (cur == 0) ? h0 : h1;
            const float* hin = (step == 0) ? hid : ((((step - 1) & 1) == 0) ? h0 : h1);
            const float* xbase;
            long xbs;
            const unsigned long long* toks;
            if (kk == 0) {
                xbase = dec + (size_t)j * D;
                xbs = (long)J * D;
                toks = nullptr;
            } else {
                xbase = emb;
                xbs = D;
                toks = argpack + ((step - 1) & 1) * 32;
            }
            unsigned long long* argz = argpack + cur * 32;
            const long outoff = (long)(j * K + kk) * V;

            k_gates<<<dim3(576), dim3(256), 0, stream>>>(
                xbase, xbs, toks, hin, wih, whh, gT);
            k_comb<<<dim3(96), dim3(256), 0, stream>>>(
                gT, bih, bhh, hin, hout, hbf, argz);
            k_voca<<<dim3(NVB + 32), dim3(256), 0, stream>>>(
                hout, hbf, embbf, enc, ids, xbase, xbs, toks, wgen, bgen,
                out, outoff, JKV, dpartT, attnw, pgenp, V, NVB);
            k_fin<<<dim3(256), dim3(256), 0, stream>>>(
                out, outoff, JKV, dpartT, NVB, attnw, pgenp, ids, argz, V);
            ++step;
        }
    }
}

// Round 4
// 2336.838 us; speedup vs baseline: 3.7636x; 1.6769x over previous
//
#include <hip/hip_runtime.h>
#include <hip/hip_bf16.h>

#define D 768
#define BB 32
#define XX 256
#define CH 3816   // vocab chunk per k_fin block (8 chunks cover 30522)

typedef __bf16 bf16x8 __attribute__((ext_vector_type(8)));
typedef float  f32x4  __attribute__((ext_vector_type(4)));

// ---------------------------------------------------------------------------
// K0: one-time: emb fp32 -> bf16
// ---------------------------------------------------------------------------
__global__ __launch_bounds__(256) void k_cvt(const float* __restrict__ src,
                                             __bf16* __restrict__ dst, int n8)
{
    int i = blockIdx.x * 256 + threadIdx.x;
    if (i < n8) {
        float4 f0 = *(const float4*)(src + (size_t)i * 8);
        float4 f1 = *(const float4*)(src + (size_t)i * 8 + 4);
        bf16x8 o;
        o[0] = (__bf16)f0.x; o[1] = (__bf16)f0.y; o[2] = (__bf16)f0.z; o[3] = (__bf16)f0.w;
        o[4] = (__bf16)f1.x; o[5] = (__bf16)f1.y; o[6] = (__bf16)f1.z; o[7] = (__bf16)f1.w;
        *(bf16x8*)(dst + (size_t)i * 8) = o;
    }
}

// ---------------------------------------------------------------------------
// K0b: one-time: penc[b][x] = wgen[1536:2304] . enc[b,x,:]  (ctx only feeds
// wgen, and that dot is step-invariant). grid 128 (32 b x 4 x-chunks of 64).
// 32 lanes per x-row, coalesced float4 loads, wgen slice in registers.
// ---------------------------------------------------------------------------
__global__ __launch_bounds__(256) void k_penc(
    const float* __restrict__ enc, const float* __restrict__ wgen,
    float* __restrict__ penc)
{
    const int t = threadIdx.x;
    const int b = blockIdx.x >> 2, c = blockIdx.x & 3;
    const int x0 = c * 64;
    const int l = t & 31;
    float4 wr[6];
    #pragma unroll
    for (int p = 0; p < 6; ++p)
        wr[p] = *(const float4*)(wgen + 1536 + l * 4 + p * 128);
    for (int g = 0; g < 8; ++g) {
        int x = x0 + g * 8 + (t >> 5);
        const float* er = enc + ((size_t)b * XX + x) * D + l * 4;
        float acc = 0.f;
        #pragma unroll
        for (int p = 0; p < 6; ++p) {
            float4 e = *(const float4*)(er + p * 128);
            acc += e.x * wr[p].x + e.y * wr[p].y + e.z * wr[p].z + e.w * wr[p].w;
        }
        #pragma unroll
        for (int m = 1; m <= 16; m <<= 1) acc += __shfl_xor(acc, m);
        if (l == 0) penc[b * XX + x] = acc;
    }
}

// ---------------------------------------------------------------------------
// K1: GRU gates GEMM, fp32. gT[row 0..4607][b 0..31]. grid 576 x 256.
// ---------------------------------------------------------------------------
__global__ __launch_bounds__(256) void k_gates(
    const float* __restrict__ xbase, long xbstride,
    const unsigned long long* __restrict__ toks,
    const float* __restrict__ hin,
    const float* __restrict__ wih, const float* __restrict__ whh,
    float* __restrict__ gT)
{
    __shared__ __align__(16) float vec[BB][132];
    __shared__ int tokl[BB];
    const int t = threadIdx.x, bid = blockIdx.x;
    const int b = t & 31, rl = t >> 5;
    const int rglob = bid * 8 + rl;
    const bool isH = rglob >= 2304;
    const int row = isH ? rglob - 2304 : rglob;
    const float* w = (isH ? whh : wih) + (size_t)row * D;
    if (t < 32) tokl[t] = toks ? (int)(0xFFFFFFFFu - (unsigned)(toks[t] & 0xFFFFFFFFull)) : 0;

    float acc = 0.f;
    for (int c = 0; c < 6; ++c) {
        const int kc = c * 128;
        __syncthreads();
        for (int p = 0; p < 4; ++p) {
            int fid = t + 256 * p;
            int bb = fid >> 5, k4 = (fid & 31) * 4;
            const float* src;
            if (isH) src = hin + (size_t)bb * D;
            else     src = toks ? (xbase + (size_t)tokl[bb] * D)
                                : (xbase + (size_t)bb * xbstride);
            *(float4*)&vec[bb][k4] = *(const float4*)(src + kc + k4);
        }
        __syncthreads();
        #pragma unroll
        for (int k4 = 0; k4 < 128; k4 += 4) {
            float4 wv = *(const float4*)(w + kc + k4);
            float4 xv = *(const float4*)&vec[b][k4];
            acc += wv.x * xv.x + wv.y * xv.y + wv.z * xv.z + wv.w * xv.w;
        }
    }
    gT[(size_t)rglob * 32 + b] = acc;
}

// ---------------------------------------------------------------------------
// K2: GRU combine -> h (fp32 + bf16); zero argz; pgen partials for
// wgen[0:768].h + wgen[768:1536].x  ->  pgen_part[b][bid]. grid 96 x 256.
// ---------------------------------------------------------------------------
__global__ __launch_bounds__(256) void k_comb(
    const float* __restrict__ gT,
    const float* __restrict__ bih, const float* __restrict__ bhh,
    const float* __restrict__ hin,
    const float* __restrict__ xbase, long xbstride,
    const unsigned long long* __restrict__ toks,
    const float* __restrict__ wgen,
    float* __restrict__ hout, __bf16* __restrict__ hbf,
    float* __restrict__ pgen_part,
    unsigned long long* __restrict__ argz)
{
    __shared__ float part[8][32];
    const int t = threadIdx.x, bid = blockIdx.x;
    const int b = t & 31, dl = t >> 5;
    const int d = bid * 8 + dl;
    if (bid == 0 && t < 32) argz[t] = 0ULL;
    float ir = gT[(size_t)d * 32 + b]            + bih[d];
    float iz = gT[(size_t)(768 + d) * 32 + b]    + bih[768 + d];
    float in_ = gT[(size_t)(1536 + d) * 32 + b]  + bih[1536 + d];
    float hr = gT[(size_t)(2304 + d) * 32 + b]   + bhh[d];
    float hz = gT[(size_t)(3072 + d) * 32 + b]   + bhh[768 + d];
    float hn = gT[(size_t)(3840 + d) * 32 + b]   + bhh[1536 + d];
    float r = 1.0f / (1.0f + expf(-(ir + hr)));
    float z = 1.0f / (1.0f + expf(-(iz + hz)));
    float n = tanhf(in_ + r * hn);
    float hold = hin[(size_t)b * D + d];
    float hv = (1.0f - z) * n + z * hold;
    hout[(size_t)b * D + d] = hv;
    hbf[(size_t)b * D + d] = (__bf16)hv;
    // pgen partial: wgen[d]*h + wgen[768+d]*x
    float xv;
    if (toks) {
        int tok = (int)(0xFFFFFFFFu - (unsigned)(toks[b] & 0xFFFFFFFFull));
        xv = xbase[(size_t)tok * D + d];
    } else {
        xv = xbase[(size_t)b * xbstride + d];
    }
    part[dl][b] = wgen[d] * hv + wgen[768 + d] * xv;
    __syncthreads();
    if (t < 32) {
        float s = 0.f;
        #pragma unroll
        for (int i = 0; i < 8; ++i) s += part[i][t];
        pgen_part[(size_t)t * 96 + bid] = s;
    }
}

// ---------------------------------------------------------------------------
// K3: vocab exp-logits via bf16 MFMA (blocks [0,NVB)) + attn logit blocks
// (NLG=128: 32 b x 4 x-chunks). Vocab writes exp(logit)+denominator partials;
// logit blocks write masked fp32 logits (coalesced, 32 lanes per x-row).
// ---------------------------------------------------------------------------
__global__ __launch_bounds__(256) void k_mid(
    const float* __restrict__ hnew, const __bf16* __restrict__ hbf,
    const __bf16* __restrict__ embbf,
    const float* __restrict__ enc, const int* __restrict__ ids,
    float* __restrict__ out, long outoff, long JKV,
    float* __restrict__ dpartT, float* __restrict__ logitw,
    int V, int NVB)
{
    __shared__ float dsum[32];
    const int t = threadIdx.x;
    const int bid = blockIdx.x;

    if (bid < NVB) {
        // -------------------- vocab MFMA block --------------------
        if (t < 32) dsum[t] = 0.f;
        __syncthreads();

        const int lane = t & 63, w = t >> 6;
        const int col = lane & 15;
        const int kq  = (lane >> 4) * 8;
        int vrow = bid * 64 + w * 16 + col;
        const bool ok = vrow < V;
        const int vl = ok ? vrow : V - 1;
        const __bf16* bp  = embbf + (size_t)vl * D + kq;
        const __bf16* ap0 = hbf + (size_t)col * D + kq;
        const __bf16* ap1 = hbf + (size_t)(col + 16) * D + kq;

        f32x4 c0 = {0.f, 0.f, 0.f, 0.f};
        f32x4 c1 = {0.f, 0.f, 0.f, 0.f};
        #pragma unroll 4
        for (int kc = 0; kc < D; kc += 32) {
            bf16x8 bv = *(const bf16x8*)(bp + kc);
            bf16x8 a0 = *(const bf16x8*)(ap0 + kc);
            bf16x8 a1 = *(const bf16x8*)(ap1 + kc);
            c0 = __builtin_amdgcn_mfma_f32_16x16x32_bf16(a0, bv, c0, 0, 0, 0);
            c1 = __builtin_amdgcn_mfma_f32_16x16x32_bf16(a1, bv, c1, 0, 0, 0);
        }
        #pragma unroll
        for (int r = 0; r < 4; ++r) {
            int b0 = (lane >> 4) * 4 + r;
            float e0 = ok ? __expf(c0[r]) : 0.f;
            float e1 = ok ? __expf(c1[r]) : 0.f;
            if (ok) {
                out[(size_t)b0 * JKV + outoff + vrow] = e0;
                out[(size_t)(b0 + 16) * JKV + outoff + vrow] = e1;
            }
            #pragma unroll
            for (int m = 1; m <= 8; m <<= 1) {
                e0 += __shfl_xor(e0, m);
                e1 += __shfl_xor(e1, m);
            }
            if (col == 0) {
                atomicAdd(&dsum[b0], e0);
                atomicAdd(&dsum[b0 + 16], e1);
            }
        }
        __syncthreads();
        if (t < 32) dpartT[(size_t)t * 512 + bid] = dsum[t];
    } else {
        // -------------------- attn logit block --------------------
        const int nb = bid - NVB;          // 0..127
        const int b = nb >> 2, c = nb & 3;
        const int x0 = c * 64;
        const int l = t & 31;
        float4 hr[6];
        #pragma unroll
        for (int p = 0; p < 6; ++p)
            hr[p] = *(const float4*)(hnew + (size_t)b * D + l * 4 + p * 128);
        for (int g = 0; g < 8; ++g) {
            int x = x0 + g * 8 + (t >> 5);
            const float* er = enc + ((size_t)b * XX + x) * D + l * 4;
            float acc = 0.f;
            #pragma unroll
            for (int p = 0; p < 6; ++p) {
                float4 e = *(const float4*)(er + p * 128);
                acc += e.x * hr[p].x + e.y * hr[p].y + e.z * hr[p].z + e.w * hr[p].w;
            }
            #pragma unroll
            for (int m = 1; m <= 16; m <<= 1) acc += __shfl_xor(acc, m);
            if (l == 0) {
                int id = ids[b * XX + x];
                logitw[b * XX + x] = (id == 0) ? -1e9f : acc;
            }
        }
    }
}

// ---------------------------------------------------------------------------
// K4: finalize. Grid = 32 b x 8 chunks. Per block: reduce denom, redundant
// softmax from logits, pgen = sigmoid(parts + aw.penc + bias), pctx scatter,
// normalize out slice, register argmax -> ONE atomicMax per block.
// ---------------------------------------------------------------------------
__global__ __launch_bounds__(256) void k_fin(
    float* __restrict__ out, long outoff, long JKV,
    const float* __restrict__ dpartT, int npart,
    const float* __restrict__ logitw, const float* __restrict__ penc,
    const float* __restrict__ pgen_part, const float* __restrict__ bgen,
    const int* __restrict__ ids,
    unsigned long long* __restrict__ argz, int V)
{
    __shared__ float pctx[CH];
    __shared__ float red[256];
    __shared__ float aw[256];
    __shared__ unsigned long long wmax[4];
    const int t = threadIdx.x;
    const int b = blockIdx.x >> 3;
    const int c = blockIdx.x & 7;
    const int v0 = c * CH;

    // 1. denominator
    float s = 0.f;
    for (int i = t; i < npart; i += 256) s += dpartT[(size_t)b * 512 + i];
    red[t] = s;
    __syncthreads();
    for (int st = 128; st > 0; st >>= 1) {
        if (t < st) red[t] += red[t + st];
        __syncthreads();
    }
    const float rd = 1.0f / red[0];
    __syncthreads();

    // 2. attention softmax (redundant per chunk-block; 256 elems — trivial)
    float l = logitw[b * XX + t];
    red[t] = l;
    __syncthreads();
    for (int st = 128; st > 0; st >>= 1) {
        if (t < st) red[t] = fmaxf(red[t], red[t + st]);
        __syncthreads();
    }
    float mx = red[0];
    __syncthreads();
    float e = expf(l - mx);
    red[t] = e;
    __syncthreads();
    for (int st = 128; st > 0; st >>= 1) {
        if (t < st) red[t] += red[t + st];
        __syncthreads();
    }
    float awv = e / red[0];
    aw[t] = awv;
    __syncthreads();

    // 3. p_gen
    float pv = awv * penc[b * XX + t] + ((t < 96) ? pgen_part[(size_t)b * 96 + t] : 0.f);
    red[t] = pv;
    __syncthreads();
    for (int st = 128; st > 0; st >>= 1) {
        if (t < st) red[t] += red[t + st];
        __syncthreads();
    }
    const float pg = 1.0f / (1.0f + expf(-(red[0] + bgen[0])));
    const float og = 1.0f - pg;

    // 4. scatter p_ctx chunk
    for (int i = t; i < CH; i += 256) pctx[i] = 0.f;
    __syncthreads();
    {
        int id = ids[b * XX + t];
        int rel = id - v0;
        if ((unsigned)rel < (unsigned)CH) atomicAdd(&pctx[rel], aw[t]);
    }
    __syncthreads();

    // 5. normalize + argmax
    unsigned long long pk = 0ULL;
    const int vend = (v0 + CH < V) ? CH : (V - v0);
    #pragma unroll
    for (int i = 0; i < 15; ++i) {
        int v = t + 256 * i;
        if (v < vend) {
            int vg = v0 + v;
            size_t o = (size_t)b * JKV + outoff + vg;
            float ev = out[o];
            float ps = pg * ev * rd + og * pctx[v];
            out[o] = ps;
            unsigned long long k2 = ((unsigned long long)__float_as_uint(ps) << 32)
                                  | (unsigned long long)(0xFFFFFFFFu - (unsigned)vg);
            if (k2 > pk) pk = k2;
        }
    }
    #pragma unroll
    for (int m = 1; m < 64; m <<= 1) {
        unsigned long long o2 = __shfl_xor(pk, m);
        if (o2 > pk) pk = o2;
    }
    if ((t & 63) == 0) wmax[t >> 6] = pk;
    __syncthreads();
    if (t == 0) {
        unsigned long long m0 = wmax[0];
        #pragma unroll
        for (int i2 = 1; i2 < 4; ++i2) if (wmax[i2] > m0) m0 = wmax[i2];
        atomicMax(&argz[b], m0);
    }
}

// ---------------------------------------------------------------------------
extern "C" void kernel_launch(void* const* d_in, const int* in_sizes, int n_in,
                              void* d_out, int out_size, void* d_ws, size_t ws_size,
                              hipStream_t stream)
{
    const float* dec  = (const float*)d_in[0];
    const float* hid  = (const float*)d_in[1];
    const float* enc  = (const float*)d_in[2];
    const int*   ids  = (const int*)d_in[3];
    const float* emb  = (const float*)d_in[5];
    const float* wih  = (const float*)d_in[6];
    const float* whh  = (const float*)d_in[7];
    const float* bih  = (const float*)d_in[8];
    const float* bhh  = (const float*)d_in[9];
    const float* wgen = (const float*)d_in[10];
    const float* bgen = (const float*)d_in[11];
    float* out = (float*)d_out;

    const int B = 32;
    const int J = in_sizes[0] / (B * D);           // 4
    const int V = in_sizes[5] / D;                 // 30522
    const int K = out_size / (B * J * V);          // 8
    const long JKV = (long)J * K * V;
    const int NVB = (V + 63) / 64;                 // 477
    const int NLG = 128;                           // attn logit blocks

    // workspace carve
    char* w = (char*)d_ws;
    unsigned long long* argpack = (unsigned long long*)w; w += 1024; // 2 x 32
    float* gT        = (float*)w;  w += (size_t)4608 * 32 * 4;
    float* dpartT    = (float*)w;  w += (size_t)32 * 512 * 4;
    float* logitw    = (float*)w;  w += (size_t)B * XX * 4;
    float* penc      = (float*)w;  w += (size_t)B * XX * 4;
    float* pgen_part = (float*)w;  w += (size_t)B * 96 * 4;
    float* h0        = (float*)w;  w += (size_t)B * D * 4;
    float* h1        = (float*)w;  w += (size_t)B * D * 4;
    __bf16* hbf      = (__bf16*)w; w += (size_t)B * D * 2;
    __bf16* embbf    = (__bf16*)w; w += (size_t)V * D * 2;

    const int n8 = V * D / 8;
    k_cvt<<<dim3((n8 + 255) / 256), dim3(256), 0, stream>>>(emb, embbf, n8);
    k_penc<<<dim3(128), dim3(256), 0, stream>>>(enc, wgen, penc);

    int step = 0;
    for (int j = 0; j < J; ++j) {
        for (int kk = 0; kk < K; ++kk) {
            const int cur = step & 1;
            float* hout = (cur == 0) ? h0 : h1;
            const float* hin = (step == 0) ? hid : ((((step - 1) & 1) == 0) ? h0 : h1);
            const float* xbase;
            long xbs;
            const unsigned long long* toks;
            if (kk == 0) {
                xbase = dec + (size_t)j * D;
                xbs = (long)J * D;
                toks = nullptr;
            } else {
                xbase = emb;
                xbs = D;
                toks = argpack + ((step - 1) & 1) * 32;
            }
            unsigned long long* argz = argpack + cur * 32;
            const long outoff = (long)(j * K + kk) * V;

            k_gates<<<dim3(576), dim3(256), 0, stream>>>(
                xbase, xbs, toks, hin, wih, whh, gT);
            k_comb<<<dim3(96), dim3(256), 0, stream>>>(
                gT, bih, bhh, hin, xbase, xbs, toks, wgen, hout, hbf,
                pgen_part, argz);
            k_mid<<<dim3(NVB + NLG), dim3(256), 0, stream>>>(
                hout, hbf, embbf, enc, ids, out, outoff, JKV,
                dpartT, logitw, V, NVB);
            k_fin<<<dim3(256), dim3(256), 0, stream>>>(
                out, outoff, JKV, dpartT, NVB, logitw, penc, pgen_part,
                bgen, ids, argz, V);
            ++step;
        }
    }
}